// Round 7
// baseline (186.871 us; speedup 1.0000x reference)
//
#include <hip/hip_runtime.h>
#include <hip/hip_bf16.h>
#include <stdint.h>

#define N    8192
#define D    256
#define NCLS 100

static constexpr float TEMP    = 0.5f;
static constexpr float SCALE_F = 1.69864360f;  // sqrt(log2e/TEMP)
static constexpr float E2      = 7.38905609893065f;
static constexpr float LN2     = 0.69314718055994531f;

typedef __bf16 bf16x8 __attribute__((ext_vector_type(8)));
typedef float  f32x4  __attribute__((ext_vector_type(4)));

__device__ __forceinline__ unsigned short f2bf(float f) {
  union { float f; unsigned int u; } x; x.f = f;
  unsigned int r = x.u + 0x7fffu + ((x.u >> 16) & 1u);
  return (unsigned short)(r >> 16);
}
__device__ __forceinline__ float bf2f(unsigned short b) {
  union { unsigned int u; float f; } x; x.u = ((unsigned int)b) << 16;
  return x.f;
}

__global__ __launch_bounds__(256) void normalize_kernel(
    const float* __restrict__ emb, const long long* __restrict__ label,
    unsigned short* __restrict__ abf, int* __restrict__ cnt,
    int* __restrict__ list) {
  const int row  = blockIdx.x * 4 + (threadIdx.x >> 6);
  const int lane = threadIdx.x & 63;
  const float4 v = ((const float4*)(emb + (size_t)row * D))[lane];
  float ss = v.x * v.x + v.y * v.y + v.z * v.z + v.w * v.w;
#pragma unroll
  for (int off = 1; off < 64; off <<= 1) ss += __shfl_xor(ss, off);
  const float s = rsqrtf(ss) * SCALE_F;
  ushort4 o;
  o.x = f2bf(v.x * s); o.y = f2bf(v.y * s);
  o.z = f2bf(v.z * s); o.w = f2bf(v.w * s);
  ((ushort4*)(abf + (size_t)row * D))[lane] = o;
  if (lane == 0) {
    const int c = (int)label[row];
    const int slot = atomicAdd(cnt + c, 1);
    list[c * 256 + slot] = row;
  }
}

// ---- Kernel B: barrier-free register GEMM. One 128x128 triangle tile per
// block; each of the 4 waves autonomously computes a 32x128 strip with
// A-frags resident and B-frags streamed global->VGPR (double-buffered).
// No LDS / no __syncthreads in the K-loop at all.
#define TM 128

__global__ __launch_bounds__(256) void simexp_rowsum_kernel(
    const unsigned short* __restrict__ A, float* __restrict__ rowsum) {
  __shared__ float cred[4][128];
  const int tid  = threadIdx.x;
  const int w    = tid >> 6;
  const int lane = tid & 63;
  const int quad = lane >> 4;
  const int l15  = lane & 15;

  // decode linear triangle id -> (bi, bj), bj >= bi
  const int id = blockIdx.x;
  int bi = (int)((129.0f - sqrtf(16641.0f - 8.0f * (float)id)) * 0.5f);
  while (bi > 0 && (bi * (129 - bi)) / 2 > id) --bi;
  while (((bi + 1) * (128 - bi)) / 2 <= id) ++bi;
  const int bj   = bi + (id - (bi * (129 - bi)) / 2);
  const int row0 = bi * TM;
  const int jb0  = bj * TM;
  const bool diag = (bi == bj);

  // A-fragments: wave w owns rows row0 + w*32 .. +31.
  // frag layout: m = l15, k = ks*32 + quad*8 + j  (16B contiguous per lane)
  const unsigned short* Abase =
      A + (size_t)(row0 + w * 32 + l15) * D + quad * 8;
  bf16x8 af[2][8];
#pragma unroll
  for (int mt = 0; mt < 2; ++mt)
#pragma unroll
    for (int ks = 0; ks < 8; ++ks)
      af[mt][ks] = *(const bf16x8*)(Abase + mt * 16 * D + ks * 32);

  const unsigned short* Bbase = A + (size_t)(jb0 + l15) * D + quad * 8;

  f32x4 acc[2][8];
#pragma unroll
  for (int mt = 0; mt < 2; ++mt)
#pragma unroll
    for (int nt = 0; nt < 8; ++nt) acc[mt][nt] = (f32x4){0.f, 0.f, 0.f, 0.f};

  // K-loop: stream B-frags with a 2-deep register pipeline; MFMA overlaps
  // the next round's loads (compiler emits vmcnt(N) waits, never a drain).
  bf16x8 b0[8], b1[8];
#pragma unroll
  for (int nt = 0; nt < 8; ++nt)
    b0[nt] = *(const bf16x8*)(Bbase + nt * 16 * D);
#pragma unroll
  for (int ks = 0; ks < 8; ++ks) {
    bf16x8* cur = (ks & 1) ? b1 : b0;
    bf16x8* nxt = (ks & 1) ? b0 : b1;
    if (ks < 7) {
#pragma unroll
      for (int nt = 0; nt < 8; ++nt)
        nxt[nt] = *(const bf16x8*)(Bbase + nt * 16 * D + (ks + 1) * 32);
    }
#pragma unroll
    for (int nt = 0; nt < 8; ++nt) {
      acc[0][nt] = __builtin_amdgcn_mfma_f32_16x16x32_bf16(af[0][ks], cur[nt],
                                                           acc[0][nt], 0, 0, 0);
      acc[1][nt] = __builtin_amdgcn_mfma_f32_16x16x32_bf16(af[1][ks], cur[nt],
                                                           acc[1][nt], 0, 0, 0);
    }
  }

  // Epilogue. C layout: col = l15, row-in-16 = quad*4 + e.
  float cs[8];
#pragma unroll
  for (int nt = 0; nt < 8; ++nt) cs[nt] = 0.f;
#pragma unroll
  for (int mt = 0; mt < 2; ++mt) {
    float rp[4] = {0.f, 0.f, 0.f, 0.f};
#pragma unroll
    for (int nt = 0; nt < 8; ++nt)
#pragma unroll
      for (int e = 0; e < 4; ++e) {
        const float v = __builtin_amdgcn_exp2f(acc[mt][nt][e]);
        rp[e] += v;
        cs[nt] += v;
      }
#pragma unroll
    for (int e = 0; e < 4; ++e) {
      float v = rp[e];
      v += __shfl_xor(v, 1);
      v += __shfl_xor(v, 2);
      v += __shfl_xor(v, 4);
      v += __shfl_xor(v, 8);
      if (l15 == 0)
        atomicAdd(&rowsum[row0 + w * 32 + mt * 16 + quad * 4 + e], v);
    }
  }

  // Column sums via symmetry: per-wave quad-reduce, cross-wave via LDS,
  // 128 atomics per block. Barriers only here, after all MFMA work.
  if (!diag) {
#pragma unroll
    for (int nt = 0; nt < 8; ++nt) {
      float v = cs[nt];
      v += __shfl_xor(v, 16);
      v += __shfl_xor(v, 32);
      if (quad == 0) cred[w][nt * 16 + l15] = v;
    }
    __syncthreads();
    if (tid < 128)
      atomicAdd(&rowsum[jb0 + tid],
                cred[0][tid] + cred[1][tid] + cred[2][tid] + cred[3][tid]);
  }
}

__global__ __launch_bounds__(256) void finalize_kernel(
    const unsigned short* __restrict__ abf, const float* __restrict__ rowsum,
    const long long* __restrict__ label, const int* __restrict__ cnt,
    const int* __restrict__ list, float* __restrict__ out) {
  __shared__ float red[4];
  __shared__ int rows_l[256];
  const int tid  = threadIdx.x;
  const int w    = tid >> 6;
  const int lane = tid & 63;

  if (blockIdx.x < NCLS) {
    const int c = blockIdx.x;
    const int m = cnt[c];
    if (m <= 1) return;
    if (tid < m) rows_l[tid] = list[c * 256 + tid];
    __syncthreads();
    float acc = 0.f;
    for (int s = 0; s < m; ++s)
      acc += bf2f(abf[(size_t)rows_l[s] * D + tid]);
    float v = acc * acc;
#pragma unroll
    for (int off = 1; off < 64; off <<= 1) v += __shfl_xor(v, off);
    if (lane == 0) red[w] = v;
    __syncthreads();
    if (tid == 0) {
      const float ssq = red[0] + red[1] + red[2] + red[3];
      const float term = (ssq * LN2 - 2.0f * (float)m) / (float)(m - 1);
      atomicAdd(out, -term);
    }
  } else {
    const int i = (blockIdx.x - NCLS) * 256 + tid;
    const int c = (int)label[i];
    float v = 0.f;
    if (cnt[c] > 1)
      v = __builtin_amdgcn_logf(rowsum[i] - E2) * LN2;
#pragma unroll
    for (int off = 1; off < 64; off <<= 1) v += __shfl_xor(v, off);
    if (lane == 0) red[w] = v;
    __syncthreads();
    if (tid == 0)
      atomicAdd(out, red[0] + red[1] + red[2] + red[3]);
  }
}

extern "C" void kernel_launch(void* const* d_in, const int* in_sizes, int n_in,
                              void* d_out, int out_size, void* d_ws,
                              size_t ws_size, hipStream_t stream) {
  const float* emb = (const float*)d_in[0];
  const long long* label = (const long long*)d_in[1];
  float* out = (float*)d_out;

  char* ws = (char*)d_ws;
  unsigned short* abf = (unsigned short*)ws;           // 4 MB
  float* rowsum = (float*)(ws + (size_t)N * D * 2);    // N floats
  int* cnt = (int*)(rowsum + N);                       // 128 ints (100 used)
  int* list = cnt + 128;                               // NCLS*256 ints

  hipMemsetAsync(rowsum, 0, (size_t)N * 4 + 128 * 4, stream);
  hipMemsetAsync(out, 0, sizeof(float), stream);

  normalize_kernel<<<N / 4, 256, 0, stream>>>(emb, label, abf, cnt, list);

  // 2080 upper-triangle tiles, one per block, barrier-free K-loop
  simexp_rowsum_kernel<<<2080, 256, 0, stream>>>(abf, rowsum);

  finalize_kernel<<<NCLS + N / 256, 256, 0, stream>>>(abf, rowsum, label, cnt,
                                                      list, out);
}

// Round 8
// 133.374 us; speedup vs baseline: 1.4011x; 1.4011x over previous
//
#include <hip/hip_runtime.h>
#include <hip/hip_bf16.h>
#include <stdint.h>

#define N    8192
#define D    256
#define NCLS 100

static constexpr float TEMP    = 0.5f;
static constexpr float SCALE_F = 1.69864360f;  // sqrt(log2e/TEMP)
static constexpr float E2      = 7.38905609893065f;
static constexpr float LN2     = 0.69314718055994531f;

typedef float f32x4 __attribute__((ext_vector_type(4)));

__device__ __forceinline__ unsigned short f2bf(float f) {
  union { float f; unsigned int u; } x; x.f = f;
  unsigned int r = x.u + 0x7fffu + ((x.u >> 16) & 1u);
  return (unsigned short)(r >> 16);
}
__device__ __forceinline__ float bf2f(unsigned short b) {
  union { unsigned int u; float f; } x; x.u = ((unsigned int)b) << 16;
  return x.f;
}
__device__ __forceinline__ void gld16(const void* g, void* l) {
  __builtin_amdgcn_global_load_lds(
      (const __attribute__((address_space(1))) unsigned int*)g,
      (__attribute__((address_space(3))) unsigned int*)l, 16, 0, 0);
}

// ---- Kernel A: row-normalize; write bf16 copy (for class sums) and fp8
// e4m3 copy (for the GEMM), both with SCALE_F folded in.
__global__ __launch_bounds__(256) void normalize_kernel(
    const float* __restrict__ emb, const long long* __restrict__ label,
    unsigned short* __restrict__ abf, unsigned char* __restrict__ a8,
    int* __restrict__ cnt, int* __restrict__ list) {
  const int row  = blockIdx.x * 4 + (threadIdx.x >> 6);
  const int lane = threadIdx.x & 63;
  const float4 v = ((const float4*)(emb + (size_t)row * D))[lane];
  float ss = v.x * v.x + v.y * v.y + v.z * v.z + v.w * v.w;
#pragma unroll
  for (int off = 1; off < 64; off <<= 1) ss += __shfl_xor(ss, off);
  const float s = rsqrtf(ss) * SCALE_F;
  const float x = v.x * s, y = v.y * s, z = v.z * s, wv = v.w * s;

  ushort4 o;
  o.x = f2bf(x); o.y = f2bf(y); o.z = f2bf(z); o.w = f2bf(wv);
  ((ushort4*)(abf + (size_t)row * D))[lane] = o;

  int p = __builtin_amdgcn_cvt_pk_fp8_f32(x, y, 0, false);
  p = __builtin_amdgcn_cvt_pk_fp8_f32(z, wv, p, true);
  ((int*)(a8 + (size_t)row * D))[lane] = p;

  if (lane == 0) {
    const int c = (int)label[row];
    const int slot = atomicAdd(cnt + c, 1);
    list[c * 256 + slot] = row;
  }
}

// ---- Kernel B: r2's proven structure, fp8 operands, BK=128 elements.
// LDS rows are 128 B; 16B-block XOR-swizzle with (row>>1)&7 -> every bank
// serves exactly 2 lanes (free), and gld16 16B contiguity is preserved.
#define TM 128
#define TN 128
#define BKB 128  // K-chunk in elements (= bytes, fp8)
#define JT 4

__global__ __launch_bounds__(256) void simexp_rowsum_kernel(
    const unsigned char* __restrict__ A, float* __restrict__ rowsum) {
  __shared__ __align__(16) unsigned char sa[TM * BKB];  // 16 KB
  __shared__ __align__(16) unsigned char sb[TN * BKB];  // 16 KB
  const int tid  = threadIdx.x;
  const int w    = tid >> 6;
  const int lane = tid & 63;
  const int quad = lane >> 4;
  const int l15  = lane & 15;
  const int row0 = blockIdx.y * TM;
  const int jc0  = blockIdx.x * (TN * JT);
  const int wm   = (w & 1) * 64;
  const int wn   = (w >> 1) * 64;
  const int srow = lane >> 3;                      // 0..7 rows per wave-load
  const int sblk = lane & 7;                       // 16B block within 128B row

  float rowpart[4][4];
#pragma unroll
  for (int mt = 0; mt < 4; ++mt)
#pragma unroll
    for (int e = 0; e < 4; ++e) rowpart[mt][e] = 0.f;

  for (int jt = 0; jt < JT; ++jt) {
    const int jbase = jc0 + jt * TN;
    f32x4 acc[4][4];
#pragma unroll
    for (int mt = 0; mt < 4; ++mt)
#pragma unroll
      for (int nt = 0; nt < 4; ++nt) acc[mt][nt] = (f32x4){0.f, 0.f, 0.f, 0.f};

    for (int kc = 0; kc < D; kc += BKB) {
#pragma unroll
      for (int p = 0; p < 4; ++p) {
        const int seg = p * 4 + w;                 // wave-uniform 0..15
        const int r   = seg * 8 + srow;            // tile row this lane loads
        const int sc  = kc + ((sblk ^ ((r >> 1) & 7)) << 4);
        gld16(A + (size_t)(row0 + r) * D + sc, sa + seg * 1024);
        gld16(A + (size_t)(jbase + r) * D + sc, sb + seg * 1024);
      }
      __syncthreads();
#pragma unroll
      for (int kk = 0; kk < 4; ++kk) {             // 4 K-steps of 32
        const int b16 = kk * 2 + (quad >> 1);      // 16B block 0..7
        const int s8  = (quad & 1) * 8;
        long af[4], bf[4];
#pragma unroll
        for (int mt = 0; mt < 4; ++mt) {
          const int m = wm + mt * 16 + l15;
          af[mt] = *(const long*)(sa + m * BKB +
                                  ((b16 ^ ((m >> 1) & 7)) << 4) + s8);
        }
#pragma unroll
        for (int nt = 0; nt < 4; ++nt) {
          const int n = wn + nt * 16 + l15;
          bf[nt] = *(const long*)(sb + n * BKB +
                                  ((b16 ^ ((n >> 1) & 7)) << 4) + s8);
        }
#pragma unroll
        for (int mt = 0; mt < 4; ++mt)
#pragma unroll
          for (int nt = 0; nt < 4; ++nt)
            acc[mt][nt] = __builtin_amdgcn_mfma_f32_16x16x32_fp8_fp8(
                af[mt], bf[nt], acc[mt][nt], 0, 0, 0);
      }
      __syncthreads();
    }

    // epilogue: exp2 of every sim element, accumulate row partials
#pragma unroll
    for (int mt = 0; mt < 4; ++mt)
#pragma unroll
      for (int nt = 0; nt < 4; ++nt)
#pragma unroll
        for (int e = 0; e < 4; ++e)
          rowpart[mt][e] += __builtin_amdgcn_exp2f(acc[mt][nt][e]);
  }

  // C layout: col = l15, row-in-16 = quad*4 + e. Reduce over 16 cols, one
  // atomic per row per block.
#pragma unroll
  for (int mt = 0; mt < 4; ++mt)
#pragma unroll
    for (int e = 0; e < 4; ++e) {
      float v = rowpart[mt][e];
      v += __shfl_xor(v, 1);
      v += __shfl_xor(v, 2);
      v += __shfl_xor(v, 4);
      v += __shfl_xor(v, 8);
      if (l15 == 0)
        atomicAdd(&rowsum[row0 + wm + mt * 16 + quad * 4 + e], v);
    }
}

__global__ __launch_bounds__(256) void finalize_kernel(
    const unsigned short* __restrict__ abf, const float* __restrict__ rowsum,
    const long long* __restrict__ label, const int* __restrict__ cnt,
    const int* __restrict__ list, float* __restrict__ out) {
  __shared__ float red[4];
  __shared__ int rows_l[256];
  const int tid  = threadIdx.x;
  const int w    = tid >> 6;
  const int lane = tid & 63;

  if (blockIdx.x < NCLS) {
    const int c = blockIdx.x;
    const int m = cnt[c];
    if (m <= 1) return;
    if (tid < m) rows_l[tid] = list[c * 256 + tid];
    __syncthreads();
    float acc = 0.f;
    for (int s = 0; s < m; ++s)
      acc += bf2f(abf[(size_t)rows_l[s] * D + tid]);
    float v = acc * acc;
#pragma unroll
    for (int off = 1; off < 64; off <<= 1) v += __shfl_xor(v, off);
    if (lane == 0) red[w] = v;
    __syncthreads();
    if (tid == 0) {
      const float ssq = red[0] + red[1] + red[2] + red[3];
      const float term = (ssq * LN2 - 2.0f * (float)m) / (float)(m - 1);
      atomicAdd(out, -term);
    }
  } else {
    const int i = (blockIdx.x - NCLS) * 256 + tid;
    const int c = (int)label[i];
    float v = 0.f;
    if (cnt[c] > 1)
      v = __builtin_amdgcn_logf(rowsum[i] - E2) * LN2;
#pragma unroll
    for (int off = 1; off < 64; off <<= 1) v += __shfl_xor(v, off);
    if (lane == 0) red[w] = v;
    __syncthreads();
    if (tid == 0)
      atomicAdd(out, red[0] + red[1] + red[2] + red[3]);
  }
}

extern "C" void kernel_launch(void* const* d_in, const int* in_sizes, int n_in,
                              void* d_out, int out_size, void* d_ws,
                              size_t ws_size, hipStream_t stream) {
  const float* emb = (const float*)d_in[0];
  const long long* label = (const long long*)d_in[1];
  float* out = (float*)d_out;

  char* ws = (char*)d_ws;
  unsigned short* abf = (unsigned short*)ws;            // 4 MB bf16
  unsigned char* a8 = (unsigned char*)(ws + (size_t)N * D * 2);  // 2 MB fp8
  float* rowsum = (float*)(ws + (size_t)N * D * 3);     // N floats
  int* cnt = (int*)(rowsum + N);                        // 128 ints
  int* list = cnt + 128;                                // NCLS*256 ints

  hipMemsetAsync(rowsum, 0, (size_t)N * 4 + 128 * 4, stream);
  hipMemsetAsync(out, 0, sizeof(float), stream);

  normalize_kernel<<<N / 4, 256, 0, stream>>>(emb, label, abf, a8, cnt, list);

  dim3 gridB(N / (TN * JT), N / TM);  // (16, 64) -> 1024 blocks, r2 balance
  simexp_rowsum_kernel<<<gridB, 256, 0, stream>>>(a8, rowsum);

  finalize_kernel<<<NCLS + N / 256, 256, 0, stream>>>(abf, rowsum, label, cnt,
                                                      list, out);
}

// Round 9
// 132.850 us; speedup vs baseline: 1.4066x; 1.0039x over previous
//
#include <hip/hip_runtime.h>
#include <hip/hip_bf16.h>
#include <stdint.h>

#define N    8192
#define D    256
#define NCLS 100

static constexpr float TEMP    = 0.5f;
static constexpr float SCALE_F = 1.69864360f;  // sqrt(log2e/TEMP)
static constexpr float E2      = 7.38905609893065f;
static constexpr float LN2     = 0.69314718055994531f;

typedef float f32x4 __attribute__((ext_vector_type(4)));

__device__ __forceinline__ unsigned short f2bf(float f) {
  union { float f; unsigned int u; } x; x.f = f;
  unsigned int r = x.u + 0x7fffu + ((x.u >> 16) & 1u);
  return (unsigned short)(r >> 16);
}
__device__ __forceinline__ float bf2f(unsigned short b) {
  union { unsigned int u; float f; } x; x.u = ((unsigned int)b) << 16;
  return x.f;
}
__device__ __forceinline__ void gld16(const void* g, void* l) {
  __builtin_amdgcn_global_load_lds(
      (const __attribute__((address_space(1))) unsigned int*)g,
      (__attribute__((address_space(3))) unsigned int*)l, 16, 0, 0);
}

// fp8 fragment-major layout:
//   addr(r, k) = (r>>4)*4096 + (k>>3)*128 + (r&15)*8 + (k&7)
// -> GEMM LDS reads are lane-linear 128B segments (0 bank conflicts);
// -> staging is a flat contiguous copy.

// ---- Kernel A: row-normalize; bf16 row-major copy (class sums) + fp8 e4m3
// fragment-major copy (GEMM), SCALE_F folded into both.
__global__ __launch_bounds__(256) void normalize_kernel(
    const float* __restrict__ emb, const long long* __restrict__ label,
    unsigned short* __restrict__ abf, unsigned char* __restrict__ a8,
    int* __restrict__ cnt, int* __restrict__ list) {
  const int row  = blockIdx.x * 4 + (threadIdx.x >> 6);
  const int lane = threadIdx.x & 63;
  const float4 v = ((const float4*)(emb + (size_t)row * D))[lane];
  float ss = v.x * v.x + v.y * v.y + v.z * v.z + v.w * v.w;
#pragma unroll
  for (int off = 1; off < 64; off <<= 1) ss += __shfl_xor(ss, off);
  const float s = rsqrtf(ss) * SCALE_F;
  const float x = v.x * s, y = v.y * s, z = v.z * s, wv = v.w * s;

  ushort4 o;
  o.x = f2bf(x); o.y = f2bf(y); o.z = f2bf(z); o.w = f2bf(wv);
  ((ushort4*)(abf + (size_t)row * D))[lane] = o;

  int p = __builtin_amdgcn_cvt_pk_fp8_f32(x, y, 0, false);
  p = __builtin_amdgcn_cvt_pk_fp8_f32(z, wv, p, true);
  // k = lane*4 .. +3 -> octet = lane>>1, 4B half = lane&1
  *(int*)(a8 + (size_t)(row >> 4) * 4096 + (lane >> 1) * 128 +
          (row & 15) * 8 + (lane & 1) * 4) = p;

  if (lane == 0) {
    const int c = (int)label[row];
    const int slot = atomicAdd(cnt + c, 1);
    list[c * 256 + slot] = row;
  }
}

// ---- Kernel B: r2 grid/balance (1024 blocks x 4 j-tiles), fp8 operands,
// fragment-major LDS with conflict-free lane-linear reads.
#define TM 128
#define TN 128
#define JT 4

__global__ __launch_bounds__(256) void simexp_rowsum_kernel(
    const unsigned char* __restrict__ A, float* __restrict__ rowsum) {
  __shared__ __align__(16) unsigned char sa[TM * 128];  // 16 KB (one kc half)
  __shared__ __align__(16) unsigned char sb[TN * 128];  // 16 KB
  const int tid  = threadIdx.x;
  const int w    = tid >> 6;
  const int lane = tid & 63;
  const int quad = lane >> 4;
  const int l15  = lane & 15;
  const int row0 = blockIdx.y * TM;
  const int jc0  = blockIdx.x * (TN * JT);
  const int pr0  = row0 >> 4;            // first 16-row panel of A-tile
  const int pam  = (w & 1) * 4;          // wave's A panel base (local)
  const int pbn  = (w >> 1) * 4;         // wave's B panel base (local)
  const int wm   = (w & 1) * 64;
  const int wn   = (w >> 1) * 64;

  float rowpart[4][4];
#pragma unroll
  for (int mt = 0; mt < 4; ++mt)
#pragma unroll
    for (int e = 0; e < 4; ++e) rowpart[mt][e] = 0.f;

  for (int jt = 0; jt < JT; ++jt) {
    const int jbase = jc0 + jt * TN;
    const int pj0   = jbase >> 4;
    f32x4 acc[4][4];
#pragma unroll
    for (int mt = 0; mt < 4; ++mt)
#pragma unroll
      for (int nt = 0; nt < 4; ++nt) acc[mt][nt] = (f32x4){0.f, 0.f, 0.f, 0.f};

#pragma unroll
    for (int kc = 0; kc < 2; ++kc) {     // two 128-element K halves
      // flat staging: seg -> (panel pp, kilobyte half), 1024 B contiguous per
      // wave-op, perfectly coalesced; LDS dest contiguous (DMA layout).
#pragma unroll
      for (int p = 0; p < 4; ++p) {
        const int seg  = p * 4 + w;      // 0..15, wave-uniform
        const int pp   = seg >> 1;
        const int half = (seg & 1) * 1024;
        const size_t goff = kc * 2048 + half + lane * 16;
        gld16(A + (size_t)(pr0 + pp) * 4096 + goff, sa + seg * 1024);
        gld16(A + (size_t)(pj0 + pp) * 4096 + goff, sb + seg * 1024);
      }
      __syncthreads();
#pragma unroll
      for (int kk = 0; kk < 4; ++kk) {   // K-steps of 32 within the half
        const int fo = (kk * 4 + quad) * 128 + l15 * 8;  // lane-linear
        long af[4], bf[4];
#pragma unroll
        for (int mt = 0; mt < 4; ++mt)
          af[mt] = *(const long*)(sa + (pam + mt) * 2048 + fo);
#pragma unroll
        for (int nt = 0; nt < 4; ++nt)
          bf[nt] = *(const long*)(sb + (pbn + nt) * 2048 + fo);
#pragma unroll
        for (int mt = 0; mt < 4; ++mt)
#pragma unroll
          for (int nt = 0; nt < 4; ++nt)
            acc[mt][nt] = __builtin_amdgcn_mfma_f32_16x16x32_fp8_fp8(
                af[mt], bf[nt], acc[mt][nt], 0, 0, 0);
      }
      __syncthreads();
    }

    // epilogue: exp2 of every sim element, accumulate row partials
#pragma unroll
    for (int mt = 0; mt < 4; ++mt)
#pragma unroll
      for (int nt = 0; nt < 4; ++nt)
#pragma unroll
        for (int e = 0; e < 4; ++e)
          rowpart[mt][e] += __builtin_amdgcn_exp2f(acc[mt][nt][e]);
  }

  // C layout: col = l15, row-in-16 = quad*4 + e. Reduce over 16 cols, one
  // atomic per row per block.
#pragma unroll
  for (int mt = 0; mt < 4; ++mt)
#pragma unroll
    for (int e = 0; e < 4; ++e) {
      float v = rowpart[mt][e];
      v += __shfl_xor(v, 1);
      v += __shfl_xor(v, 2);
      v += __shfl_xor(v, 4);
      v += __shfl_xor(v, 8);
      if (l15 == 0)
        atomicAdd(&rowsum[row0 + wm + mt * 16 + quad * 4 + e], v);
    }
  (void)wn;
}

__global__ __launch_bounds__(256) void finalize_kernel(
    const unsigned short* __restrict__ abf, const float* __restrict__ rowsum,
    const long long* __restrict__ label, const int* __restrict__ cnt,
    const int* __restrict__ list, float* __restrict__ out) {
  __shared__ float red[4];
  __shared__ int rows_l[256];
  const int tid  = threadIdx.x;
  const int w    = tid >> 6;
  const int lane = tid & 63;

  if (blockIdx.x < NCLS) {
    const int c = blockIdx.x;
    const int m = cnt[c];
    if (m <= 1) return;
    if (tid < m) rows_l[tid] = list[c * 256 + tid];
    __syncthreads();
    float acc = 0.f;
    for (int s = 0; s < m; ++s)
      acc += bf2f(abf[(size_t)rows_l[s] * D + tid]);
    float v = acc * acc;
#pragma unroll
    for (int off = 1; off < 64; off <<= 1) v += __shfl_xor(v, off);
    if (lane == 0) red[w] = v;
    __syncthreads();
    if (tid == 0) {
      const float ssq = red[0] + red[1] + red[2] + red[3];
      const float term = (ssq * LN2 - 2.0f * (float)m) / (float)(m - 1);
      atomicAdd(out, -term);
    }
  } else {
    const int i = (blockIdx.x - NCLS) * 256 + tid;
    const int c = (int)label[i];
    float v = 0.f;
    if (cnt[c] > 1)
      v = __builtin_amdgcn_logf(rowsum[i] - E2) * LN2;
#pragma unroll
    for (int off = 1; off < 64; off <<= 1) v += __shfl_xor(v, off);
    if (lane == 0) red[w] = v;
    __syncthreads();
    if (tid == 0)
      atomicAdd(out, red[0] + red[1] + red[2] + red[3]);
  }
}

extern "C" void kernel_launch(void* const* d_in, const int* in_sizes, int n_in,
                              void* d_out, int out_size, void* d_ws,
                              size_t ws_size, hipStream_t stream) {
  const float* emb = (const float*)d_in[0];
  const long long* label = (const long long*)d_in[1];
  float* out = (float*)d_out;

  char* ws = (char*)d_ws;
  unsigned short* abf = (unsigned short*)ws;            // 4 MB bf16 row-major
  unsigned char* a8 = (unsigned char*)(ws + (size_t)N * D * 2);  // 2 MB fp8
  float* rowsum = (float*)(ws + (size_t)N * D * 3);     // N floats
  int* cnt = (int*)(rowsum + N);                        // 128 ints
  int* list = cnt + 128;                                // NCLS*256 ints

  hipMemsetAsync(rowsum, 0, (size_t)N * 4 + 128 * 4, stream);
  hipMemsetAsync(out, 0, sizeof(float), stream);

  normalize_kernel<<<N / 4, 256, 0, stream>>>(emb, label, abf, a8, cnt, list);

  dim3 gridB(N / (TN * JT), N / TM);  // (16, 64) -> 1024 blocks
  simexp_rowsum_kernel<<<gridB, 256, 0, stream>>>(a8, rowsum);

  finalize_kernel<<<NCLS + N / 256, 256, 0, stream>>>(abf, rowsum, label, cnt,
                                                      list, out);
}

// Round 10
// 131.839 us; speedup vs baseline: 1.4174x; 1.0077x over previous
//
#include <hip/hip_runtime.h>
#include <hip/hip_bf16.h>
#include <stdint.h>

#define N    8192
#define D    256
#define NCLS 100

static constexpr float TEMP    = 0.5f;
static constexpr float SCALE_F = 1.69864360f;  // sqrt(log2e/TEMP)
static constexpr float E2      = 7.38905609893065f;
static constexpr float LN2     = 0.69314718055994531f;

typedef float f32x4 __attribute__((ext_vector_type(4)));

__device__ __forceinline__ unsigned short f2bf(float f) {
  union { float f; unsigned int u; } x; x.f = f;
  unsigned int r = x.u + 0x7fffu + ((x.u >> 16) & 1u);
  return (unsigned short)(r >> 16);
}
__device__ __forceinline__ float bf2f(unsigned short b) {
  union { unsigned int u; float f; } x; x.u = ((unsigned int)b) << 16;
  return x.f;
}
__device__ __forceinline__ void gld16(const void* g, void* l) {
  __builtin_amdgcn_global_load_lds(
      (const __attribute__((address_space(1))) unsigned int*)g,
      (__attribute__((address_space(3))) unsigned int*)l, 16, 0, 0);
}

// fp8 fragment-major layout:
//   addr(r, k) = (r>>4)*4096 + (k>>3)*128 + (r&15)*8 + (k&7)
// -> GEMM LDS reads are lane-linear 128B segments (0 bank conflicts);
// -> staging is a flat contiguous copy; K-halves of a panel are contiguous.

// ---- Kernel A: row-normalize; bf16 row-major copy (class sums) + fp8 e4m3
// fragment-major copy (GEMM); also zeroes rowsum (folds the memset).
__global__ __launch_bounds__(256) void normalize_kernel(
    const float* __restrict__ emb, const long long* __restrict__ label,
    unsigned short* __restrict__ abf, unsigned char* __restrict__ a8,
    float* __restrict__ rowsum, int* __restrict__ cnt,
    int* __restrict__ list) {
  const int row  = blockIdx.x * 4 + (threadIdx.x >> 6);
  const int lane = threadIdx.x & 63;
  const float4 v = ((const float4*)(emb + (size_t)row * D))[lane];
  float ss = v.x * v.x + v.y * v.y + v.z * v.z + v.w * v.w;
#pragma unroll
  for (int off = 1; off < 64; off <<= 1) ss += __shfl_xor(ss, off);
  const float s = rsqrtf(ss) * SCALE_F;
  const float x = v.x * s, y = v.y * s, z = v.z * s, wv = v.w * s;

  ushort4 o;
  o.x = f2bf(x); o.y = f2bf(y); o.z = f2bf(z); o.w = f2bf(wv);
  ((ushort4*)(abf + (size_t)row * D))[lane] = o;

  int p = __builtin_amdgcn_cvt_pk_fp8_f32(x, y, 0, false);
  p = __builtin_amdgcn_cvt_pk_fp8_f32(z, wv, p, true);
  // k = lane*4 .. +3 -> octet = lane>>1, 4B half = lane&1
  *(int*)(a8 + (size_t)(row >> 4) * 4096 + (lane >> 1) * 128 +
          (row & 15) * 8 + (lane & 1) * 4) = p;

  if (lane == 0) {
    rowsum[row] = 0.f;
    const int c = (int)label[row];
    const int slot = atomicAdd(cnt + c, 1);
    list[c * 256 + slot] = row;
  }
}

// ---- Kernel B: A-tile resident in LDS (staged once, full K); B-tile in
// half-K double buffers, prefetched one phase ahead so the vmcnt(0) drain
// at each barrier waits on loads that already had a full compute phase.
#define TM 128
#define TN 128
#define JT 4

__global__ __launch_bounds__(256) void simexp_rowsum_kernel(
    const unsigned char* __restrict__ A, float* __restrict__ rowsum) {
  __shared__ __align__(16) unsigned char sa[TM * 256];     // 32 KB, full K
  __shared__ __align__(16) unsigned char sb[2][TN * 128];  // 2 x 16 KB halves
  const int tid  = threadIdx.x;
  const int w    = tid >> 6;
  const int lane = tid & 63;
  const int quad = lane >> 4;
  const int l15  = lane & 15;
  const int row0 = blockIdx.y * TM;
  const int jc0  = blockIdx.x * (TN * JT);
  const int pr0  = row0 >> 4;      // first 16-row panel of A-tile
  const int pam  = (w & 1) * 4;    // wave's A panel base (local)
  const int pbn  = (w >> 1) * 4;   // wave's B panel base (local)
  const int wm   = (w & 1) * 64;

  // Stage full A-tile: 32 segs of 1024 B; wave w stages segs w*8..w*8+7.
#pragma unroll
  for (int p = 0; p < 8; ++p) {
    const int seg = w * 8 + p;  // wave-uniform
    gld16(A + (size_t)(pr0 + (seg >> 2)) * 4096 + (seg & 3) * 1024 + lane * 16,
          sa + seg * 1024);
  }
  // Stage B(jt=0, kc=0) into buffer 0.
#pragma unroll
  for (int p = 0; p < 4; ++p) {
    const int seg = w * 4 + p;
    gld16(A + (size_t)((jc0 >> 4) + (seg >> 1)) * 4096 + (seg & 1) * 1024 +
              lane * 16,
          sb[0] + seg * 1024);
  }
  __syncthreads();

  float rowpart[4][4];
#pragma unroll
  for (int mt = 0; mt < 4; ++mt)
#pragma unroll
    for (int e = 0; e < 4; ++e) rowpart[mt][e] = 0.f;

  int buf = 0;
  for (int jt = 0; jt < JT; ++jt) {
    f32x4 acc[4][4];
#pragma unroll
    for (int mt = 0; mt < 4; ++mt)
#pragma unroll
      for (int nt = 0; nt < 4; ++nt) acc[mt][nt] = (f32x4){0.f, 0.f, 0.f, 0.f};

#pragma unroll
    for (int kc = 0; kc < 2; ++kc) {
      // Prefetch the next half-K B chunk into the other buffer.
      if (!(jt == JT - 1 && kc == 1)) {
        const int njt = (kc == 1) ? jt + 1 : jt;
        const int nkc = kc ^ 1;
        const int pj0 = (jc0 + njt * TN) >> 4;
#pragma unroll
        for (int p = 0; p < 4; ++p) {
          const int seg = w * 4 + p;
          gld16(A + (size_t)(pj0 + (seg >> 1)) * 4096 + nkc * 2048 +
                    (seg & 1) * 1024 + lane * 16,
                sb[buf ^ 1] + seg * 1024);
        }
      }
      // Compute from sb[buf] against the kc-half of resident A.
#pragma unroll
      for (int kk = 0; kk < 4; ++kk) {
        const int fo = (kk * 4 + quad) * 128 + l15 * 8;  // lane-linear
        long af[4], bf[4];
#pragma unroll
        for (int mt = 0; mt < 4; ++mt)
          af[mt] = *(const long*)(sa + (pam + mt) * 4096 + kc * 2048 + fo);
#pragma unroll
        for (int nt = 0; nt < 4; ++nt)
          bf[nt] = *(const long*)(sb[buf] + (pbn + nt) * 2048 + fo);
#pragma unroll
        for (int mt = 0; mt < 4; ++mt)
#pragma unroll
          for (int nt = 0; nt < 4; ++nt)
            acc[mt][nt] = __builtin_amdgcn_mfma_f32_16x16x32_fp8_fp8(
                af[mt], bf[nt], acc[mt][nt], 0, 0, 0);
      }
      __syncthreads();
      buf ^= 1;
    }

    // epilogue: exp2 of every sim element, accumulate row partials
#pragma unroll
    for (int mt = 0; mt < 4; ++mt)
#pragma unroll
      for (int nt = 0; nt < 4; ++nt)
#pragma unroll
        for (int e = 0; e < 4; ++e)
          rowpart[mt][e] += __builtin_amdgcn_exp2f(acc[mt][nt][e]);
  }

  // C layout: col = l15, row-in-16 = quad*4 + e. Reduce over 16 cols, one
  // atomic per row per block.
#pragma unroll
  for (int mt = 0; mt < 4; ++mt)
#pragma unroll
    for (int e = 0; e < 4; ++e) {
      float v = rowpart[mt][e];
      v += __shfl_xor(v, 1);
      v += __shfl_xor(v, 2);
      v += __shfl_xor(v, 4);
      v += __shfl_xor(v, 8);
      if (l15 == 0)
        atomicAdd(&rowsum[row0 + wm + mt * 16 + quad * 4 + e], v);
    }
}

__global__ __launch_bounds__(256) void finalize_kernel(
    const unsigned short* __restrict__ abf, const float* __restrict__ rowsum,
    const long long* __restrict__ label, const int* __restrict__ cnt,
    const int* __restrict__ list, float* __restrict__ out) {
  __shared__ float red[4];
  __shared__ int rows_l[256];
  const int tid  = threadIdx.x;
  const int w    = tid >> 6;
  const int lane = tid & 63;

  if (blockIdx.x < NCLS) {
    const int c = blockIdx.x;
    const int m = cnt[c];
    if (m <= 1) return;
    if (tid < m) rows_l[tid] = list[c * 256 + tid];
    __syncthreads();
    float acc = 0.f;
    for (int s = 0; s < m; ++s)
      acc += bf2f(abf[(size_t)rows_l[s] * D + tid]);
    float v = acc * acc;
#pragma unroll
    for (int off = 1; off < 64; off <<= 1) v += __shfl_xor(v, off);
    if (lane == 0) red[w] = v;
    __syncthreads();
    if (tid == 0) {
      const float ssq = red[0] + red[1] + red[2] + red[3];
      const float term = (ssq * LN2 - 2.0f * (float)m) / (float)(m - 1);
      atomicAdd(out, -term);
    }
  } else {
    const int i = (blockIdx.x - NCLS) * 256 + tid;
    const int c = (int)label[i];
    float v = 0.f;
    if (cnt[c] > 1)
      v = __builtin_amdgcn_logf(rowsum[i] - E2) * LN2;
#pragma unroll
    for (int off = 1; off < 64; off <<= 1) v += __shfl_xor(v, off);
    if (lane == 0) red[w] = v;
    __syncthreads();
    if (tid == 0)
      atomicAdd(out, red[0] + red[1] + red[2] + red[3]);
  }
}

extern "C" void kernel_launch(void* const* d_in, const int* in_sizes, int n_in,
                              void* d_out, int out_size, void* d_ws,
                              size_t ws_size, hipStream_t stream) {
  const float* emb = (const float*)d_in[0];
  const long long* label = (const long long*)d_in[1];
  float* out = (float*)d_out;

  char* ws = (char*)d_ws;
  unsigned short* abf = (unsigned short*)ws;            // 4 MB bf16 row-major
  unsigned char* a8 = (unsigned char*)(ws + (size_t)N * D * 2);  // 2 MB fp8
  float* rowsum = (float*)(ws + (size_t)N * D * 3);     // N floats
  int* cnt = (int*)(rowsum + N);                        // 128 ints
  int* list = cnt + 128;                                // NCLS*256 ints

  hipMemsetAsync(cnt, 0, 128 * 4, stream);
  hipMemsetAsync(out, 0, sizeof(float), stream);

  normalize_kernel<<<N / 4, 256, 0, stream>>>(emb, label, abf, a8, rowsum,
                                              cnt, list);

  dim3 gridB(N / (TN * JT), N / TM);  // (16, 64) -> 1024 blocks
  simexp_rowsum_kernel<<<gridB, 256, 0, stream>>>(a8, rowsum);

  finalize_kernel<<<NCLS + N / 256, 256, 0, stream>>>(abf, rowsum, label, cnt,
                                                      list, out);
}